// Round 3
// baseline (250.420 us; speedup 1.0000x reference)
//
#include <hip/hip_runtime.h>
#include <cstddef>

// ---------------------------------------------------------------------------
// GCN forward: 3 x ( h@W bf16 MFMA -> packed-bf16 xw -> CSR segsum+LN(+ReLU) )
// N=50000, E=800000, D: 128 -> 128 -> 128 -> 64.
// R16 = R15 with the gather rebuilt as a global_load_lds DMA RING:
//  - Per wave: 9-slot x 1KB LDS ring, 8 DMAs always in flight, consumed with
//    literal s_waitcnt vmcnt(7). In-flight data lives in LDS, not VGPRs ->
//    high occupancy AND deep MLP (16 waves/CU x 8KB outstanding).
//  - Edge cols for the wave's 4 contiguous nodes preloaded into 2 VGPRs,
//    looked up per stage via ds_bpermute (L<=128 fast path; slow fallback).
//  - Invalid/dummy lanes DMA a 256B zero row -> branch-free accumulate.
//  - Slot-reuse race eliminated: consume's ds_read retires (lgkmcnt(0) before
//    its VALU use) ahead of the sched_barrier(0)-pinned reissue.
// ---------------------------------------------------------------------------

typedef __attribute__((ext_vector_type(8))) short bf16x8;
typedef __attribute__((ext_vector_type(4))) float floatx4;
typedef __attribute__((ext_vector_type(4))) unsigned int uintx4;

static __device__ __forceinline__ unsigned int f2bf(float f) {
    union { float f; unsigned int u; } v; v.f = f;
    unsigned int u = v.u;
    u += 0x7fffu + ((u >> 16) & 1u);
    return u >> 16;
}
static __device__ __forceinline__ float bf_lo(unsigned int p) {
    union { unsigned int u; float f; } v; v.u = p << 16; return v.f;
}
static __device__ __forceinline__ float bf_hi(unsigned int p) {
    union { unsigned int u; float f; } v; v.u = p & 0xffff0000u; return v.f;
}
static __device__ __forceinline__ void acc8(float* a, uintx4 v) {
    a[0] += bf_lo(v.x); a[1] += bf_hi(v.x);
    a[2] += bf_lo(v.y); a[3] += bf_hi(v.y);
    a[4] += bf_lo(v.z); a[5] += bf_hi(v.z);
    a[6] += bf_lo(v.w); a[7] += bf_hi(v.w);
}

static __device__ __forceinline__ void gload16(const void* g, void* l) {
    __builtin_amdgcn_global_load_lds(
        (const __attribute__((address_space(1))) void*)g,
        (__attribute__((address_space(3))) void*)l, 16, 0, 0);
}

// ---- W[k][n] fp32 -> FRAGMENT-ORDERED WtF, 3 matrices (+ zero row) ---------
__global__ __launch_bounds__(256) void cvt_w(const float* __restrict__ W0,
                                             const float* __restrict__ W1,
                                             const float* __restrict__ W2,
                                             unsigned int* __restrict__ WtF,
                                             unsigned int* __restrict__ zrow) {
    if (blockIdx.x == 0 && threadIdx.x < 64) zrow[threadIdx.x] = 0u;
    const int m = blockIdx.x >> 4;
    const int slice = blockIdx.x & 15;
    const float* W = (m == 0) ? W0 : (m == 1) ? W1 : W2;
    const int ncols = (m == 2) ? 64 : 128;
    unsigned int* dst = WtF + m * 128 * 64;
    const int total = ncols * 64;                  // uints
    for (int idx = slice * 256 + threadIdx.x; idx < total; idx += 16 * 256) {
        const int j    = idx & 3;
        const int lane = (idx >> 2) & 63;
        const int s    = (idx >> 8) & 3;
        const int t    = idx >> 10;
        const int mcol = lane & 15;
        const int quad = lane >> 4;
        const int n = t * 16 + mcol;
        const int k = s * 32 + quad * 8 + 2 * j;
        unsigned int lo = f2bf(W[(size_t)k * ncols + n]);
        unsigned int hi = f2bf(W[(size_t)(k + 1) * ncols + n]);
        dst[idx] = (hi << 16) | lo;
    }
}

// ---- bf16 MFMA GEMM, 1 wave per block (16 rows x NCOLS) --------------------
// Layer 0 only: A fp32 row-major (feat), in-register bf16 convert.
template <int NCOLS, bool A_FP32>
__global__ __launch_bounds__(64) void gemm_mfma(const void* __restrict__ Av,
                                                const unsigned int* __restrict__ Wt,
                                                unsigned int* __restrict__ C,
                                                int M) {
    const int lane = threadIdx.x;
    const int row0 = blockIdx.x * 16;
    const int quad = lane >> 4;
    const int mcol = lane & 15;

    constexpr int NT = NCOLS / 16;
    floatx4 acc[NT];
    #pragma unroll
    for (int t = 0; t < NT; ++t) acc[t] = (floatx4){0.f, 0.f, 0.f, 0.f};

    int aidx = row0 + mcol; if (aidx >= M) aidx = M - 1;
    const float*        arowF = (const float*)Av + (size_t)aidx * 128 + quad * 8;
    const unsigned int* afrag = (const unsigned int*)Av + (size_t)blockIdx.x * 1024 + lane * 4;
    const unsigned int* bbase = Wt + lane * 4;

    #pragma unroll
    for (int s = 0; s < 4; ++s) {
        bf16x8 a;
        if constexpr (A_FP32) {
            float4 fa = *(const float4*)(arowF + s * 32);
            float4 fb = *(const float4*)(arowF + s * 32 + 4);
            uintx4 ap;
            ap.x = (f2bf(fa.y) << 16) | f2bf(fa.x);
            ap.y = (f2bf(fa.w) << 16) | f2bf(fa.z);
            ap.z = (f2bf(fb.y) << 16) | f2bf(fb.x);
            ap.w = (f2bf(fb.w) << 16) | f2bf(fb.z);
            a = __builtin_bit_cast(bf16x8, ap);
        } else {
            uintx4 ap = *(const uintx4*)(afrag + s * 256);
            a = __builtin_bit_cast(bf16x8, ap);
        }
        #pragma unroll
        for (int t = 0; t < NT; ++t) {
            uintx4 bp = *(const uintx4*)(bbase + t * 1024 + s * 256);
            bf16x8 b = __builtin_bit_cast(bf16x8, bp);
            acc[t] = __builtin_amdgcn_mfma_f32_16x16x32_bf16(a, b, acc[t], 0, 0, 0);
        }
    }

    const int rowStride = NCOLS >> 1;
    #pragma unroll
    for (int t = 0; t < NT; ++t) {
        #pragma unroll
        for (int r = 0; r < 4; ++r) {
            unsigned int mybf = f2bf(acc[t][r]);
            unsigned int pair = __shfl_xor(mybf, 1, 64);
            int orow = row0 + quad * 4 + r;
            if (orow < M && (mcol & 1) == 0) {
                unsigned int packed = (pair << 16) | mybf;
                C[(size_t)orow * rowStride + t * 8 + (mcol >> 1)] = packed;
            }
        }
    }
}

// ---- DMA-ring gather core: fills acc[4][8] for 4 consecutive nodes ---------
// ROWB = bytes per xw row (256 for D=128, 128 for D=64).
// Lane split: sl = lane % (ROWB/16) owns 16B of the row; g = lane / (ROWB/16)
// is the edge-group. Stage = 1 node x (64/(ROWB/16)) offsets = 1 KB DMA.
template <int ROWB>
static __device__ __forceinline__ void gather_ring(
        const unsigned int* __restrict__ xw,
        const int* __restrict__ ptr,
        const int* __restrict__ col,
        const unsigned int* __restrict__ zrow,
        unsigned int* ringw, int lane, int first, int N, int Emax,
        float acc[4][8]) {
    constexpr int SLANES = ROWB / 16;       // 16 or 8 sublanes per row
    constexpr int OSTEP  = 64 / SLANES;     // 4 or 8 edges per stage
    const int g  = lane / SLANES;
    const int sl = lane % SLANES;

    int s0[4], len[4];
    int maxlen = 0;
    #pragma unroll
    for (int n = 0; n < 4; ++n) {
        const int nn = first + n;
        const int nc = nn < N ? nn : N - 1;
        const int a = ptr[nc];
        const int b = nn < N ? ptr[nc + 1] : a;
        s0[n] = a; len[n] = b - a;
        maxlen = max(maxlen, len[n]);
    }
    const int base = s0[0];
    const int Ltot = s0[3] + len[3] - base;

    if (Ltot <= 128) {
        // cols for the wave's contiguous edge range, in 2 VGPRs
        const int colv0 = col[min(base + lane, Emax)];
        const int colv1 = col[min(base + 64 + lane, Emax)];
        const int rounds = (maxlen + OSTEP - 1) / OSTEP;

        auto issue = [&](int s0n, int lenn, int s_, int slot_) {
            const int idx = (s_ >> 2) * OSTEP + g;
            const int p = (s0n - base) + idx;
            const int cc0 = __builtin_amdgcn_ds_bpermute(p << 2, colv0);
            const int cc1 = __builtin_amdgcn_ds_bpermute((p - 64) << 2, colv1);
            const unsigned int cc = (p < 64) ? (unsigned int)cc0 : (unsigned int)cc1;
            const char* ga = (idx < lenn)
                ? ((const char*)xw + (size_t)cc * ROWB + sl * 16)
                : ((const char*)zrow + sl * 16);
            gload16(ga, (void*)(ringw + slot_ * 256));
        };

        // prologue: 8 DMAs in flight (stages past the real range self-dummy
        // because idx >= lenn selects the zero row)
        #pragma unroll
        for (int i = 0; i < 8; ++i) issue(s0[i & 3], len[i & 3], i, i);

        int si = 8, sc = 0;
        for (int r = 0; r < rounds; ++r) {
            #pragma unroll
            for (int n = 0; n < 4; ++n) {
                // oldest of 8 outstanding DMAs has landed
                asm volatile("s_waitcnt vmcnt(7)" ::: "memory");
                uintx4 v = *(const uintx4*)(ringw + sc * 256 + lane * 4);
                acc8(acc[n], v);
                // pin the slot-reissue after the consume's lgkmcnt-retired use
                __builtin_amdgcn_sched_barrier(0);
                issue(s0[n], len[n], r * 4 + n + 8, si);
                si = (si == 8) ? 0 : si + 1;
                sc = (sc == 8) ? 0 : sc + 1;
            }
        }
        asm volatile("s_waitcnt vmcnt(0)" ::: "memory");
    } else {
        // pathological long edge lists (essentially never): simple loop
        #pragma unroll
        for (int n = 0; n < 4; ++n) {
            for (int i = s0[n] + g; i < s0[n] + len[n]; i += OSTEP) {
                const unsigned int c = (unsigned int)col[i];
                uintx4 v = *(const uintx4*)((const char*)xw + (size_t)c * ROWB + sl * 16);
                acc8(acc[n], v);
            }
        }
    }
}

// ---- FUSED: ring-gather + LN + ReLU (D=128) -> LDS A-tile -> MFMA x W ------
template <int NCOLS_OUT>
__global__ __launch_bounds__(256) void agg_gemm(const unsigned int* __restrict__ xw,
                                                const int* __restrict__ ptr,
                                                const int* __restrict__ col,
                                                const unsigned int* __restrict__ Wt,
                                                unsigned int* __restrict__ C,
                                                const unsigned int* __restrict__ zrow,
                                                int N, int Emax) {
    __shared__ unsigned int ring[4][9][256];     // 36 KB: per-wave DMA ring
    __shared__ unsigned int atile[1024];         // 4 KB: 16x128 A-frag tile
    const int tile = blockIdx.x;
    const int wave = threadIdx.x >> 6;
    const int lane = threadIdx.x & 63;

    float acc[4][8] = {};
    gather_ring<256>(xw, ptr, col, zrow, &ring[wave][0][0], lane,
                     tile * 16 + wave * 4, N, Emax, acc);

    const int g  = lane >> 4;
    const int sl = lane & 15;
    #pragma unroll
    for (int n = 0; n < 4; ++n) {
        const int m = wave * 4 + n;
        float a8[8];
        #pragma unroll
        for (int j = 0; j < 8; ++j) {
            float t = acc[n][j];
            t += __shfl_xor(t, 16, 64);
            t += __shfl_xor(t, 32, 64);
            a8[j] = t;
        }
        float s1 = 0.f, s2 = 0.f;
        #pragma unroll
        for (int j = 0; j < 8; ++j) { s1 += a8[j]; s2 += a8[j] * a8[j]; }
        #pragma unroll
        for (int mm = 8; mm >= 1; mm >>= 1) {
            s1 += __shfl_xor(s1, mm, 64);
            s2 += __shfl_xor(s2, mm, 64);
        }
        const float mean = s1 * (1.0f / 128.0f);
        const float var  = s2 * (1.0f / 128.0f) - mean * mean;
        const float inv  = rsqrtf(var + 1e-5f);

        if (g == 0) {
            float o[8];
            #pragma unroll
            for (int j = 0; j < 8; ++j)
                o[j] = fmaxf((a8[j] - mean) * inv, 0.f);
            uintx4 p;
            p.x = (f2bf(o[1]) << 16) | f2bf(o[0]);
            p.y = (f2bf(o[3]) << 16) | f2bf(o[2]);
            p.z = (f2bf(o[5]) << 16) | f2bf(o[4]);
            p.w = (f2bf(o[7]) << 16) | f2bf(o[6]);
            *(uintx4*)(atile + (sl >> 2) * 256 + (sl & 3) * 64 + m * 4) = p;
        }
    }
    __syncthreads();

    // ---- phase 2: 16 x NCOLS_OUT MFMA, wave covers NCOLS_OUT/4 cols --------
    constexpr int WT = NCOLS_OUT / 64;           // tiles per wave (2 or 1)
    const int quad = lane >> 4;
    const int mcol = lane & 15;
    floatx4 macc[WT];
    #pragma unroll
    for (int t = 0; t < WT; ++t) macc[t] = (floatx4){0.f, 0.f, 0.f, 0.f};

    const unsigned int* bbase = Wt + lane * 4;
    #pragma unroll
    for (int s4 = 0; s4 < 4; ++s4) {
        uintx4 ap = *(const uintx4*)(atile + s4 * 256 + lane * 4);
        bf16x8 a = __builtin_bit_cast(bf16x8, ap);
        #pragma unroll
        for (int tt = 0; tt < WT; ++tt) {
            const int t = wave * WT + tt;
            uintx4 bp = *(const uintx4*)(bbase + t * 1024 + s4 * 256);
            bf16x8 b = __builtin_bit_cast(bf16x8, bp);
            macc[tt] = __builtin_amdgcn_mfma_f32_16x16x32_bf16(a, b, macc[tt], 0, 0, 0);
        }
    }

    const int rowStride = NCOLS_OUT >> 1;
    #pragma unroll
    for (int tt = 0; tt < WT; ++tt) {
        const int t = wave * WT + tt;
        #pragma unroll
        for (int r = 0; r < 4; ++r) {
            unsigned int mybf = f2bf(macc[tt][r]);
            unsigned int pair = __shfl_xor(mybf, 1, 64);
            const int orow = tile * 16 + quad * 4 + r;
            if (orow < N && (mcol & 1) == 0) {
                unsigned int packed = (pair << 16) | mybf;
                C[(size_t)orow * rowStride + t * 8 + (mcol >> 1)] = packed;
            }
        }
    }
}

// ---- final: ring-gather + LN, D=64, fp32 out, no ReLU ----------------------
// Lane split: sl = lane&7 owns 8 feats (16B), g = lane>>3 edge-group (0..7).
__global__ __launch_bounds__(256) void agg_ln64(const unsigned int* __restrict__ xw,
                                                const int* __restrict__ ptr,
                                                const int* __restrict__ col,
                                                float* __restrict__ out,
                                                const unsigned int* __restrict__ zrow,
                                                int N, int Emax) {
    __shared__ unsigned int ring[4][9][256];     // 36 KB
    const int wave = threadIdx.x >> 6;
    const int lane = threadIdx.x & 63;

    float acc[4][8] = {};
    gather_ring<128>(xw, ptr, col, zrow, &ring[wave][0][0], lane,
                     blockIdx.x * 16 + wave * 4, N, Emax, acc);

    const int g  = lane >> 3;
    const int sl = lane & 7;
    #pragma unroll
    for (int n = 0; n < 4; ++n) {
        const int node = blockIdx.x * 16 + wave * 4 + n;
        float a8[8];
        #pragma unroll
        for (int j = 0; j < 8; ++j) {
            float t = acc[n][j];
            t += __shfl_xor(t, 8, 64);
            t += __shfl_xor(t, 16, 64);
            t += __shfl_xor(t, 32, 64);
            a8[j] = t;
        }
        float s1 = 0.f, s2 = 0.f;
        #pragma unroll
        for (int j = 0; j < 8; ++j) { s1 += a8[j]; s2 += a8[j] * a8[j]; }
        #pragma unroll
        for (int mm = 4; mm >= 1; mm >>= 1) {
            s1 += __shfl_xor(s1, mm, 64);
            s2 += __shfl_xor(s2, mm, 64);
        }
        const float mean = s1 * (1.0f / 64.0f);
        const float var  = s2 * (1.0f / 64.0f) - mean * mean;
        const float inv  = rsqrtf(var + 1e-5f);

        if (g == 0 && node < N) {
            float4 o0, o1;
            o0.x = (a8[0] - mean) * inv;
            o0.y = (a8[1] - mean) * inv;
            o0.z = (a8[2] - mean) * inv;
            o0.w = (a8[3] - mean) * inv;
            o1.x = (a8[4] - mean) * inv;
            o1.y = (a8[5] - mean) * inv;
            o1.z = (a8[6] - mean) * inv;
            o1.w = (a8[7] - mean) * inv;
            *(float4*)(out + (size_t)node * 64 + sl * 8)     = o0;
            *(float4*)(out + (size_t)node * 64 + sl * 8 + 4) = o1;
        }
    }
}

extern "C" void kernel_launch(void* const* d_in, const int* in_sizes, int n_in,
                              void* d_out, int out_size, void* d_ws, size_t ws_size,
                              hipStream_t stream) {
    const float* feat = (const float*)d_in[0];   // [N,128]
    const float* W0   = (const float*)d_in[1];   // [128,128]
    const float* W1   = (const float*)d_in[2];   // [128,128]
    const float* W2   = (const float*)d_in[3];   // [128,64]
    const int*   ptr  = (const int*)d_in[4];     // [N+1]
    const int*   col  = (const int*)d_in[5];     // [E]
    // d_in[6] = edge_rows, unused (CSR ptr encodes the same segments)

    const int N = in_sizes[4] - 1;               // 50000 (= 3125 * 16)
    const int E = in_sizes[5];                   // 800000
    const int Emax = E - 1;

    unsigned int* buf0 = (unsigned int*)d_ws;                // [N,64] uint, row-major packed
    unsigned int* buf1 = buf0 + (size_t)N * 64;              // [N,64] uint, row-major packed
    unsigned int* WtP  = buf1 + (size_t)N * 64;              // 3 x frag-ordered W
    unsigned int* zrow = WtP + 3 * 128 * 64;                 // 256 B of zeros
    float*        out  = (float*)d_out;                      // [N,64]

    const int tileBlocks = (N + 15) / 16;        // 3125 (16-node tiles)

    cvt_w<<<48, 256, 0, stream>>>(W0, W1, W2, WtP, zrow);

    // Layer 0 GEMM (fp32 feat A-path, in-register convert)
    gemm_mfma<128, true><<<tileBlocks, 64, 0, stream>>>(feat, WtP, buf0, N);
    // Layer 0 agg + LN + ReLU fused with layer 1 GEMM
    agg_gemm<128><<<tileBlocks, 256, 0, stream>>>(buf0, ptr, col, WtP + 128 * 64, buf1, zrow, N, Emax);
    // Layer 1 agg + LN + ReLU fused with layer 2 GEMM (D_out=64)
    agg_gemm<64><<<tileBlocks, 256, 0, stream>>>(buf1, ptr, col, WtP + 2 * 128 * 64, buf0, zrow, N, Emax);
    // Layer 2 agg + LN (no ReLU), fp32 out
    agg_ln64<<<tileBlocks, 256, 0, stream>>>(buf0, ptr, col, out, zrow, N, Emax);
}

// Round 5
// 193.512 us; speedup vs baseline: 1.2941x; 1.2941x over previous
//
#include <hip/hip_runtime.h>
#include <cstddef>

// ---------------------------------------------------------------------------
// GCN forward: 3 x ( h@W bf16 MFMA -> packed-bf16 xw -> CSR segsum+LN(+ReLU) )
// N=50000, E=800000, D: 128 -> 128 -> 128 -> 64.
// R17 = R15 (best: 189us; R16's DMA ring REGRESSED and is dropped) plus:
//  - Gather pipeline deepened 2->3 buffers (12 gathers + 12 col loads in
//    flight per wave). __launch_bounds__(256,4) pins the 16-waves/CU VGPR
//    tier so the deeper pipeline can't drop an occupancy tier.
//  - gemm0 repacked: 4 independent 16-row tiles per 256-thread block (was
//    3125 single-wave blocks -- wasted block slots / issue slots).
// (R18 resubmission: R17 never ran -- GPU acquisition timeout.)
// ---------------------------------------------------------------------------

typedef __attribute__((ext_vector_type(8))) short bf16x8;
typedef __attribute__((ext_vector_type(4))) float floatx4;
typedef __attribute__((ext_vector_type(4))) unsigned int uintx4;
typedef __attribute__((ext_vector_type(2))) unsigned int uintx2;

static __device__ __forceinline__ unsigned int f2bf(float f) {
    union { float f; unsigned int u; } v; v.f = f;
    unsigned int u = v.u;
    u += 0x7fffu + ((u >> 16) & 1u);
    return u >> 16;
}
static __device__ __forceinline__ float bf_lo(unsigned int p) {
    union { unsigned int u; float f; } v; v.u = p << 16; return v.f;
}
static __device__ __forceinline__ float bf_hi(unsigned int p) {
    union { unsigned int u; float f; } v; v.u = p & 0xffff0000u; return v.f;
}
static __device__ __forceinline__ void acc8(float* a, uintx4 v) {
    a[0] += bf_lo(v.x); a[1] += bf_hi(v.x);
    a[2] += bf_lo(v.y); a[3] += bf_hi(v.y);
    a[4] += bf_lo(v.z); a[5] += bf_hi(v.z);
    a[6] += bf_lo(v.w); a[7] += bf_hi(v.w);
}
static __device__ __forceinline__ void acc4(float* a, uintx2 v) {
    a[0] += bf_lo(v.x); a[1] += bf_hi(v.x);
    a[2] += bf_lo(v.y); a[3] += bf_hi(v.y);
}

// ---- W[k][n] fp32 -> FRAGMENT-ORDERED WtF, 3 matrices ----------------------
__global__ __launch_bounds__(256) void cvt_w(const float* __restrict__ W0,
                                             const float* __restrict__ W1,
                                             const float* __restrict__ W2,
                                             unsigned int* __restrict__ WtF) {
    const int m = blockIdx.x >> 4;
    const int slice = blockIdx.x & 15;
    const float* W = (m == 0) ? W0 : (m == 1) ? W1 : W2;
    const int ncols = (m == 2) ? 64 : 128;
    unsigned int* dst = WtF + m * 128 * 64;
    const int total = ncols * 64;                  // uints
    for (int idx = slice * 256 + threadIdx.x; idx < total; idx += 16 * 256) {
        const int j    = idx & 3;
        const int lane = (idx >> 2) & 63;
        const int s    = (idx >> 8) & 3;
        const int t    = idx >> 10;
        const int mcol = lane & 15;
        const int quad = lane >> 4;
        const int n = t * 16 + mcol;
        const int k = s * 32 + quad * 8 + 2 * j;
        unsigned int lo = f2bf(W[(size_t)k * ncols + n]);
        unsigned int hi = f2bf(W[(size_t)(k + 1) * ncols + n]);
        dst[idx] = (hi << 16) | lo;
    }
}

// ---- bf16 MFMA GEMM: 4 waves/block, each wave an independent 16-row tile ---
// Layer 0 only: A fp32 row-major (feat), in-register bf16 convert.
template <int NCOLS, bool A_FP32>
__global__ __launch_bounds__(256) void gemm_mfma(const void* __restrict__ Av,
                                                 const unsigned int* __restrict__ Wt,
                                                 unsigned int* __restrict__ C,
                                                 int M, int tiles) {
    const int wave = threadIdx.x >> 6;
    const int lane = threadIdx.x & 63;
    const int tile = blockIdx.x * 4 + wave;
    if (tile >= tiles) return;
    const int row0 = tile * 16;
    const int quad = lane >> 4;
    const int mcol = lane & 15;

    constexpr int NT = NCOLS / 16;
    floatx4 acc[NT];
    #pragma unroll
    for (int t = 0; t < NT; ++t) acc[t] = (floatx4){0.f, 0.f, 0.f, 0.f};

    int aidx = row0 + mcol; if (aidx >= M) aidx = M - 1;
    const float*        arowF = (const float*)Av + (size_t)aidx * 128 + quad * 8;
    const unsigned int* afrag = (const unsigned int*)Av + (size_t)tile * 1024 + lane * 4;
    const unsigned int* bbase = Wt + lane * 4;

    #pragma unroll
    for (int s = 0; s < 4; ++s) {
        bf16x8 a;
        if constexpr (A_FP32) {
            float4 fa = *(const float4*)(arowF + s * 32);
            float4 fb = *(const float4*)(arowF + s * 32 + 4);
            uintx4 ap;
            ap.x = (f2bf(fa.y) << 16) | f2bf(fa.x);
            ap.y = (f2bf(fa.w) << 16) | f2bf(fa.z);
            ap.z = (f2bf(fb.y) << 16) | f2bf(fb.x);
            ap.w = (f2bf(fb.w) << 16) | f2bf(fb.z);
            a = __builtin_bit_cast(bf16x8, ap);
        } else {
            uintx4 ap = *(const uintx4*)(afrag + s * 256);
            a = __builtin_bit_cast(bf16x8, ap);
        }
        #pragma unroll
        for (int t = 0; t < NT; ++t) {
            uintx4 bp = *(const uintx4*)(bbase + t * 1024 + s * 256);
            bf16x8 b = __builtin_bit_cast(bf16x8, bp);
            acc[t] = __builtin_amdgcn_mfma_f32_16x16x32_bf16(a, b, acc[t], 0, 0, 0);
        }
    }

    const int rowStride = NCOLS >> 1;
    #pragma unroll
    for (int t = 0; t < NT; ++t) {
        #pragma unroll
        for (int r = 0; r < 4; ++r) {
            unsigned int mybf = f2bf(acc[t][r]);
            unsigned int pair = __shfl_xor(mybf, 1, 64);
            int orow = row0 + quad * 4 + r;
            if (orow < M && (mcol & 1) == 0) {
                unsigned int packed = (pair << 16) | mybf;
                C[(size_t)orow * rowStride + t * 8 + (mcol >> 1)] = packed;
            }
        }
    }
}

// ---- FUSED: CSR segsum + LN + ReLU (D=128) -> LDS A-tile -> MFMA x W -------
// Block = 16-node tile, 4 waves x 4 nodes. Wave walks its 4 nodes' edges
// CONCURRENTLY with a 3-deep software pipeline (col prefetch 3 sets ahead,
// gather triple-buffered). Then LN+ReLU, LDS A-frag tile, barrier, MFMA.
template <int NCOLS_OUT>
__global__ __launch_bounds__(256, 4) void agg_gemm(const unsigned int* __restrict__ xw,
                                                   const int* __restrict__ ptr,
                                                   const int* __restrict__ col,
                                                   const unsigned int* __restrict__ Wt,
                                                   unsigned int* __restrict__ C,
                                                   int N, int Emax /* = E-1 */) {
    __shared__ unsigned int lds[1024];           // 16 rows x 128 bf16, A-frag order
    const int tile = blockIdx.x;
    const int wave = threadIdx.x >> 6;
    const int lane = threadIdx.x & 63;
    const int g  = lane >> 4;     // 0..3 edge group
    const int sl = lane & 15;     // 0..15 sublane (owns 8 features)

    // ---- phase 1: 3-deep pipelined concurrent gather for 4 nodes ----
    int s0[4], len[4];
    int maxlen = 0;
    #pragma unroll
    for (int n = 0; n < 4; ++n) {
        const int node = tile * 16 + wave * 4 + n;
        const int nc = node < N ? node : N - 1;
        const int a = ptr[nc];
        const int b = node < N ? ptr[nc + 1] : a;
        s0[n] = a; len[n] = b - a;
        maxlen = max(maxlen, len[n]);
    }

    float acc[4][8] = {};
    const unsigned int* base = xw + sl * 4;

    if (maxlen > 0) {
        #define LOADCOL(dst, OFF)                                            \
            _Pragma("unroll")                                                \
            for (int n = 0; n < 4; ++n) {                                    \
                int idx = (OFF) + g;                                         \
                idx = idx < len[n] ? idx : 0;                                \
                int ei = s0[n] + idx;                                        \
                ei = ei < Emax ? ei : Emax;                                  \
                dst[n] = col[ei];                                            \
            }
        #define GATHER4(dst, c)                                              \
            _Pragma("unroll")                                                \
            for (int n = 0; n < 4; ++n)                                      \
                dst[n] = *(const uintx4*)(base + (size_t)c[n] * 64);
        #define ACCUM4(v, OFF)                                               \
            _Pragma("unroll")                                                \
            for (int n = 0; n < 4; ++n)                                      \
                if ((OFF) + g < len[n]) acc8(acc[n], v[n]);

        int c0[4], c1[4], c2[4];
        uintx4 vA[4], vB[4], vC[4];
        LOADCOL(c0, 0)
        LOADCOL(c1, 4)
        LOADCOL(c2, 8)
        GATHER4(vA, c0)
        LOADCOL(c0, 12)
        GATHER4(vB, c1)
        LOADCOL(c1, 16)
        GATHER4(vC, c2)
        LOADCOL(c2, 20)

        for (int off = 0; off < maxlen; off += 12) {
            ACCUM4(vA, off)
            GATHER4(vA, c0)            // data for off+12
            LOADCOL(c0, off + 24)
            ACCUM4(vB, off + 4)
            GATHER4(vB, c1)            // data for off+16
            LOADCOL(c1, off + 28)
            ACCUM4(vC, off + 8)
            GATHER4(vC, c2)            // data for off+20
            LOADCOL(c2, off + 32)
        }
        #undef LOADCOL
        #undef GATHER4
        #undef ACCUM4
    }

    // ---- LN + ReLU per node, write LDS A-frag tile ----
    #pragma unroll
    for (int n = 0; n < 4; ++n) {
        const int m = wave * 4 + n;
        float a8[8];
        #pragma unroll
        for (int j = 0; j < 8; ++j) {
            float t = acc[n][j];
            t += __shfl_xor(t, 16, 64);
            t += __shfl_xor(t, 32, 64);
            a8[j] = t;
        }
        float s1 = 0.f, s2 = 0.f;
        #pragma unroll
        for (int j = 0; j < 8; ++j) { s1 += a8[j]; s2 += a8[j] * a8[j]; }
        #pragma unroll
        for (int mm = 8; mm >= 1; mm >>= 1) {
            s1 += __shfl_xor(s1, mm, 64);
            s2 += __shfl_xor(s2, mm, 64);
        }
        const float mean = s1 * (1.0f / 128.0f);
        const float var  = s2 * (1.0f / 128.0f) - mean * mean;
        const float inv  = rsqrtf(var + 1e-5f);

        if (g == 0) {
            float o[8];
            #pragma unroll
            for (int j = 0; j < 8; ++j)
                o[j] = fmaxf((a8[j] - mean) * inv, 0.f);
            uintx4 p;
            p.x = (f2bf(o[1]) << 16) | f2bf(o[0]);
            p.y = (f2bf(o[3]) << 16) | f2bf(o[2]);
            p.z = (f2bf(o[5]) << 16) | f2bf(o[4]);
            p.w = (f2bf(o[7]) << 16) | f2bf(o[6]);
            *(uintx4*)(lds + (sl >> 2) * 256 + (sl & 3) * 64 + m * 4) = p;
        }
    }
    __syncthreads();

    // ---- phase 2: 16 x NCOLS_OUT MFMA, wave covers NCOLS_OUT/4 cols --------
    constexpr int WT = NCOLS_OUT / 64;           // tiles per wave (2 or 1)
    const int quad = lane >> 4;
    const int mcol = lane & 15;
    floatx4 macc[WT];
    #pragma unroll
    for (int t = 0; t < WT; ++t) macc[t] = (floatx4){0.f, 0.f, 0.f, 0.f};

    const unsigned int* bbase = Wt + lane * 4;
    #pragma unroll
    for (int s4 = 0; s4 < 4; ++s4) {
        uintx4 ap = *(const uintx4*)(lds + s4 * 256 + lane * 4);
        bf16x8 a = __builtin_bit_cast(bf16x8, ap);
        #pragma unroll
        for (int tt = 0; tt < WT; ++tt) {
            const int t = wave * WT + tt;
            uintx4 bp = *(const uintx4*)(bbase + t * 1024 + s4 * 256);
            bf16x8 b = __builtin_bit_cast(bf16x8, bp);
            macc[tt] = __builtin_amdgcn_mfma_f32_16x16x32_bf16(a, b, macc[tt], 0, 0, 0);
        }
    }

    const int rowStride = NCOLS_OUT >> 1;
    #pragma unroll
    for (int tt = 0; tt < WT; ++tt) {
        const int t = wave * WT + tt;
        #pragma unroll
        for (int r = 0; r < 4; ++r) {
            unsigned int mybf = f2bf(macc[tt][r]);
            unsigned int pair = __shfl_xor(mybf, 1, 64);
            const int orow = tile * 16 + quad * 4 + r;
            if (orow < N && (mcol & 1) == 0) {
                unsigned int packed = (pair << 16) | mybf;
                C[(size_t)orow * rowStride + t * 8 + (mcol >> 1)] = packed;
            }
        }
    }
}

// ---- final: CSR segsum + LN, D=64, fp32 out, no ReLU -----------------------
// Same 3-deep pipelined 4-nodes-per-wave structure; 16 nodes per block.
__global__ __launch_bounds__(256, 4) void agg_ln64(const unsigned int* __restrict__ xw,
                                                   const int* __restrict__ ptr,
                                                   const int* __restrict__ col,
                                                   float* __restrict__ out,
                                                   int N, int Emax) {
    const int tile = blockIdx.x;
    const int wave = threadIdx.x >> 6;
    const int lane = threadIdx.x & 63;
    const int g  = lane >> 4;     // 0..3 edge group
    const int sl = lane & 15;     // 0..15 sublane (owns 4 features)

    int s0[4], len[4];
    int maxlen = 0;
    #pragma unroll
    for (int n = 0; n < 4; ++n) {
        const int node = tile * 16 + wave * 4 + n;
        const int nc = node < N ? node : N - 1;
        const int a = ptr[nc];
        const int b = node < N ? ptr[nc + 1] : a;
        s0[n] = a; len[n] = b - a;
        maxlen = max(maxlen, len[n]);
    }

    float acc[4][4] = {};
    const unsigned int* base = xw + sl * 2;

    if (maxlen > 0) {
        #define LOADCOL(dst, OFF)                                            \
            _Pragma("unroll")                                                \
            for (int n = 0; n < 4; ++n) {                                    \
                int idx = (OFF) + g;                                         \
                idx = idx < len[n] ? idx : 0;                                \
                int ei = s0[n] + idx;                                        \
                ei = ei < Emax ? ei : Emax;                                  \
                dst[n] = col[ei];                                            \
            }
        #define GATHER2(dst, c)                                              \
            _Pragma("unroll")                                                \
            for (int n = 0; n < 4; ++n)                                      \
                dst[n] = *(const uintx2*)(base + (size_t)c[n] * 32);
        #define ACCUM2(v, OFF)                                               \
            _Pragma("unroll")                                                \
            for (int n = 0; n < 4; ++n)                                      \
                if ((OFF) + g < len[n]) acc4(acc[n], v[n]);

        int c0[4], c1[4], c2[4];
        uintx2 vA[4], vB[4], vC[4];
        LOADCOL(c0, 0)
        LOADCOL(c1, 4)
        LOADCOL(c2, 8)
        GATHER2(vA, c0)
        LOADCOL(c0, 12)
        GATHER2(vB, c1)
        LOADCOL(c1, 16)
        GATHER2(vC, c2)
        LOADCOL(c2, 20)

        for (int off = 0; off < maxlen; off += 12) {
            ACCUM2(vA, off)
            GATHER2(vA, c0)
            LOADCOL(c0, off + 24)
            ACCUM2(vB, off + 4)
            GATHER2(vB, c1)
            LOADCOL(c1, off + 28)
            ACCUM2(vC, off + 8)
            GATHER2(vC, c2)
            LOADCOL(c2, off + 32)
        }
        #undef LOADCOL
        #undef GATHER2
        #undef ACCUM2
    }

    #pragma unroll
    for (int n = 0; n < 4; ++n) {
        const int node = tile * 16 + wave * 4 + n;
        float a4[4];
        #pragma unroll
        for (int j = 0; j < 4; ++j) {
            float t = acc[n][j];
            t += __shfl_xor(t, 16, 64);
            t += __shfl_xor(t, 32, 64);
            a4[j] = t;
        }
        float s1 = 0.f, s2 = 0.f;
        #pragma unroll
        for (int j = 0; j < 4; ++j) { s1 += a4[j]; s2 += a4[j] * a4[j]; }
        #pragma unroll
        for (int mm = 8; mm >= 1; mm >>= 1) {
            s1 += __shfl_xor(s1, mm, 64);
            s2 += __shfl_xor(s2, mm, 64);
        }
        const float mean = s1 * (1.0f / 64.0f);
        const float var  = s2 * (1.0f / 64.0f) - mean * mean;
        const float inv  = rsqrtf(var + 1e-5f);

        if (g == 0 && node < N) {
            float4 o;
            o.x = (a4[0] - mean) * inv;
            o.y = (a4[1] - mean) * inv;
            o.z = (a4[2] - mean) * inv;
            o.w = (a4[3] - mean) * inv;
            *(float4*)(out + (size_t)node * 64 + sl * 4) = o;
        }
    }
}

extern "C" void kernel_launch(void* const* d_in, const int* in_sizes, int n_in,
                              void* d_out, int out_size, void* d_ws, size_t ws_size,
                              hipStream_t stream) {
    const float* feat = (const float*)d_in[0];   // [N,128]
    const float* W0   = (const float*)d_in[1];   // [128,128]
    const float* W1   = (const float*)d_in[2];   // [128,128]
    const float* W2   = (const float*)d_in[3];   // [128,64]
    const int*   ptr  = (const int*)d_in[4];     // [N+1]
    const int*   col  = (const int*)d_in[5];     // [E]
    // d_in[6] = edge_rows, unused (CSR ptr encodes the same segments)

    const int N = in_sizes[4] - 1;               // 50000 (= 3125 * 16)
    const int E = in_sizes[5];                   // 800000
    const int Emax = E - 1;

    unsigned int* buf0 = (unsigned int*)d_ws;                // [N,64] uint, row-major packed
    unsigned int* buf1 = buf0 + (size_t)N * 64;              // [N,64] uint, row-major packed
    unsigned int* WtP  = buf1 + (size_t)N * 64;              // 3 x frag-ordered W
    float*        out  = (float*)d_out;                      // [N,64]

    const int tiles = (N + 15) / 16;             // 3125 (16-node tiles)

    cvt_w<<<48, 256, 0, stream>>>(W0, W1, W2, WtP);

    // Layer 0 GEMM (fp32 feat A-path), 4 tiles per 256-thread block
    gemm_mfma<128, true><<<(tiles + 3) / 4, 256, 0, stream>>>(feat, WtP, buf0, N, tiles);
    // Layer 0 agg + LN + ReLU fused with layer 1 GEMM
    agg_gemm<128><<<tiles, 256, 0, stream>>>(buf0, ptr, col, WtP + 128 * 64, buf1, N, Emax);
    // Layer 1 agg + LN + ReLU fused with layer 2 GEMM (D_out=64)
    agg_gemm<64><<<tiles, 256, 0, stream>>>(buf1, ptr, col, WtP + 2 * 128 * 64, buf0, N, Emax);
    // Layer 2 agg + LN (no ReLU), fp32 out
    agg_ln64<<<tiles, 256, 0, stream>>>(buf0, ptr, col, out, N, Emax);
}